// Round 6
// baseline (2802.012 us; speedup 1.0000x reference)
//
#include <hip/hip_runtime.h>
#include <stdint.h>

// ---------------------------------------------------------------------------
// GINEncoder: 2x GINEConv(eps=0, MLP 128->128->128, edge_lin 32->128) + head.
//   R13: ONE persistent kernel. R5's 11 launches carried ~100-200us of
//   launch/drain overhead (cross-round launch-count regression: ~3.5-12us per
//   boundary; per-kernel rooflines sum to ~70us vs 286us measured non-agg).
//   All phases merged into gine_all<<<1024,256>>> with hand-rolled device-
//   scope grid barriers (per-sync-point counters, AGENT-scope acq_rel
//   atomics; zeroed by one hipMemsetAsync node). Co-residency guaranteed:
//   __launch_bounds__(256,4) forces VGPR<=128 (4 waves/SIMD) and LDS is
//   34.8KB/block -> 4 blocks/CU x 256 CU = 1024 = grid size.
//   Phases: [zero|wprep|wprep_we|xprep0] -> hist -> bsum -> scan -> expand ->
//   [scatter|wrange] -> agg0 -> mlp0(+fused xprep1) -> agg1 -> mlp1 -> head.
//   agg/mlp bodies are the verbatim R5 kernels (agg 92us verified, VGPR 64;
//   mlp2 with fused next-layer xprep). __restrict__ dropped (buffers alias
//   across phases within one kernel).
// edge_index is int64 in the reference but harness passes int32.
// ---------------------------------------------------------------------------

#define ND 128
#define ED 32
#define LP 132  // padded LDS row stride (floats)
#define GB 1024
#define GT (GB * 256)
#define NWAVES (GB * 4)

typedef __attribute__((ext_vector_type(8))) short short8;
typedef __attribute__((ext_vector_type(4))) float f32x4;

__device__ inline unsigned short bf16_hi(float f) {
    union { float f; unsigned u; } v;
    v.f = f;
    return (unsigned short)(v.u >> 16);  // truncation; residual captured by lo
}
__device__ inline float bf16_f(unsigned short h) {
    union { unsigned u; float f; } v;
    v.u = ((unsigned)h) << 16;
    return v.f;
}

struct GParams {
    const float* x; const int* ei; const float* ea;
    const float* w10; const float* b10; const float* w20; const float* b20;
    const float* we0; const float* be0;
    const float* w11; const float* b11; const float* w21; const float* b21;
    const float* we1; const float* be1;
    const float* fc1w; const float* fc1b; const float* fc2w; const float* fc2b;
    int N, E, NB;
    int* counts; int* row_start; int* woff; int* bsum; int* bofs; int* wstart;
    int* bar;
    int2* pack;
    unsigned short* wfh; unsigned short* wfl; unsigned short* weh;
    unsigned short* xpk;
    float* bufA; float* out;
};

// Device-scope grid barrier; one fresh counter per sync point (no reset race).
__device__ inline void gsync(int* bar, int k) {
    __syncthreads();
    if (threadIdx.x == 0) {
        __hip_atomic_fetch_add(&bar[k], 1, __ATOMIC_ACQ_REL, __HIP_MEMORY_SCOPE_AGENT);
        while (__hip_atomic_load(&bar[k], __ATOMIC_ACQUIRE, __HIP_MEMORY_SCOPE_AGENT) < GB)
            __builtin_amdgcn_s_sleep(2);
    }
    __syncthreads();
}

// Node-centric MFMA aggregation over a contiguous, edge-balanced node range.
// h[v] = x[v] + sum_{e: dst=v} relu((x[src_e]+be) + ea_e @ we)
// (verbatim R5 body; early return is fine -- caller syncs afterwards)
__device__ void agg_body(const float* xin, const float* edge_attr,
                         const unsigned short* xpk, const unsigned short* bfh,
                         const int* row_start, const int* wstart, const int2* pack,
                         float* hout, int N, int E) {
    int lane = threadIdx.x & 63;
    int gw = (blockIdx.x * blockDim.x + threadIdx.x) >> 6;
    int m = lane & 15;
    int quad = lane >> 4;

    short8 bh[8];
#pragma unroll
    for (int nt = 0; nt < 8; ++nt)
        bh[nt] = *(const short8*)(bfh + ((size_t)nt * 64 + lane) * 8);

    short8 idf[2];
#pragma unroll
    for (int q = 0; q < 2; ++q)
#pragma unroll
        for (int j = 0; j < 8; ++j)
            idf[q][j] = (quad * 8 + j == q * 16 + m) ? (short)0x3F80 : (short)0;

    int col0 = quad * 32 + m;
    int col1 = col0 + 16;

    int v_lo = wstart[gw];
    int v_hi = wstart[gw + 1];
    if (v_lo >= v_hi) return;

    int beg = row_start[v_lo];
    int2 pk2 = pack[min(beg + m, E - 1)];

    for (int v = v_lo; v < v_hi; ++v) {
        int end = row_start[v + 1];
        float res0 = xin[(size_t)v * ND + col0];
        float res1 = xin[(size_t)v * ND + col1];
        float part[8];
#pragma unroll
        for (int nt = 0; nt < 8; ++nt) part[nt] = 0.f;

        for (int base = beg; base < end; base += 16) {
            int2 pk = pk2;
            int nxt = (base + 16 < end) ? base + 16 : end;
            pk2 = pack[min(nxt + m, E - 1)];

            int rem = end - base;  // >= 1
            int s = (m < rem) ? pk.x : N;  // sentinel row kills pad lanes in relu

            const unsigned short* xr = xpk + ((size_t)s * 16 + quad) * 16;
            short8 xh[4], xl[4];
#pragma unroll
            for (int kc = 0; kc < 4; ++kc) {
                xh[kc] = *(const short8*)(xr + kc * 64);
                xl[kc] = *(const short8*)(xr + kc * 64 + 8);
            }
            const float4* ar = (const float4*)(edge_attr + (size_t)pk.y * ED + quad * 8);
            float4 a0 = ar[0], a1 = ar[1];

            float af[8] = {a0.x, a0.y, a0.z, a0.w, a1.x, a1.y, a1.z, a1.w};
            short8 ah, al;
#pragma unroll
            for (int j = 0; j < 8; ++j) {
                unsigned short h = bf16_hi(af[j]);
                ah[j] = (short)h;
                al[j] = (short)bf16_hi(af[j] - bf16_f(h));
            }

#pragma unroll
            for (int nt = 0; nt < 8; ++nt) {
                f32x4 a = {0.f, 0.f, 0.f, 0.f};
                a = __builtin_amdgcn_mfma_f32_16x16x32_bf16(ah, bh[nt], a, 0, 0, 0);
                a = __builtin_amdgcn_mfma_f32_16x16x32_bf16(al, bh[nt], a, 0, 0, 0);
                a = __builtin_amdgcn_mfma_f32_16x16x32_bf16(xh[nt >> 1], idf[nt & 1], a,
                                                            0, 0, 0);
                a = __builtin_amdgcn_mfma_f32_16x16x32_bf16(xl[nt >> 1], idf[nt & 1], a,
                                                            0, 0, 0);
#pragma unroll
                for (int r = 0; r < 4; ++r)
                    part[nt] += fmaxf(a[r], 0.f);  // be already inside xpk
            }
        }
#pragma unroll
        for (int nt = 0; nt < 8; ++nt) {
            float p = part[nt];
            p += __shfl_xor(p, 16, 64);
            p += __shfl_xor(p, 32, 64);
            part[nt] = p;
        }
        float o0 = quad == 0 ? part[0] : quad == 1 ? part[2] : quad == 2 ? part[4] : part[6];
        float o1 = quad == 0 ? part[1] : quad == 1 ? part[3] : quad == 2 ? part[5] : part[7];
        hout[(size_t)v * ND + col0] = res0 + o0;
        hout[(size_t)v * ND + col1] = res1 + o1;
        beg = end;
    }
}

// Fused pair of GEMMs: C = maybe_relu2( relu(A@W1+b1) @ W2 + b2 ).
// Wave = 16 rows via per-wave LDS tile T; grid-stride over row-tiles.
// If xpk != nullptr also emits next-layer xpk fragments of (C + ben).
__device__ void mlp_body(const float* A, const unsigned short* w1h,
                         const unsigned short* w1l, const float* b1,
                         const unsigned short* w2h, const unsigned short* w2l,
                         const float* b2, float* C, int N, int relu2,
                         const float* ben, unsigned short* xpk, float* T) {
    int lane = threadIdx.x & 63;
    int wave = threadIdx.x >> 6;
    int m = lane & 15;
    int quad = lane >> 4;

    for (int gw = blockIdx.x * 4 + wave; gw * 16 < N; gw += GB * 4) {
        int m0 = gw * 16;

        // ---- stage 1: load A rows, split hi/lo ----
        int row = m0 + m;
        bool rok = row < N;
        short8 ah[4], al[4];
#pragma unroll
        for (int ks = 0; ks < 4; ++ks) {
            float f[8];
            if (rok) {
                const float4* p =
                    (const float4*)(A + (size_t)row * ND + ks * 32 + quad * 8);
                float4 a0 = p[0], a1 = p[1];
                f[0] = a0.x; f[1] = a0.y; f[2] = a0.z; f[3] = a0.w;
                f[4] = a1.x; f[5] = a1.y; f[6] = a1.z; f[7] = a1.w;
            } else {
#pragma unroll
                for (int j = 0; j < 8; ++j) f[j] = 0.f;
            }
#pragma unroll
            for (int j = 0; j < 8; ++j) {
                unsigned short hh = bf16_hi(f[j]);
                ah[ks][j] = (short)hh;
                al[ks][j] = (short)bf16_hi(f[j] - bf16_f(hh));
            }
        }

        // GEMM1 -> bias + relu -> LDS tile
#pragma unroll
        for (int nt = 0; nt < 8; ++nt) {
            f32x4 acc = {0.f, 0.f, 0.f, 0.f};
#pragma unroll
            for (int ks = 0; ks < 4; ++ks) {
                size_t off = ((size_t)(nt * 4 + ks) * 64 + lane) * 8;
                short8 bh = *(const short8*)(w1h + off);
                short8 bl = *(const short8*)(w1l + off);
                acc = __builtin_amdgcn_mfma_f32_16x16x32_bf16(ah[ks], bh, acc, 0, 0, 0);
                acc = __builtin_amdgcn_mfma_f32_16x16x32_bf16(al[ks], bh, acc, 0, 0, 0);
                acc = __builtin_amdgcn_mfma_f32_16x16x32_bf16(ah[ks], bl, acc, 0, 0, 0);
            }
            float bv = b1[nt * 16 + m];
#pragma unroll
            for (int r = 0; r < 4; ++r) {
                float o = acc[r] + bv;
                o = o > 0.f ? o : 0.f;
                T[(quad * 4 + r) * LP + nt * 16 + m] = o;
            }
        }

        // ---- stage 2: rows from LDS as A-fragments (same-wave lgkmcnt) ----
        short8 ch[4], cl[4];
#pragma unroll
        for (int ks = 0; ks < 4; ++ks) {
            const float4* p = (const float4*)(T + m * LP + ks * 32 + quad * 8);
            float4 a0 = p[0], a1 = p[1];
            float f[8] = {a0.x, a0.y, a0.z, a0.w, a1.x, a1.y, a1.z, a1.w};
#pragma unroll
            for (int j = 0; j < 8; ++j) {
                unsigned short hh = bf16_hi(f[j]);
                ch[ks][j] = (short)hh;
                cl[ks][j] = (short)bf16_hi(f[j] - bf16_f(hh));
            }
        }

#pragma unroll
        for (int nt = 0; nt < 8; ++nt) {
            f32x4 acc = {0.f, 0.f, 0.f, 0.f};
#pragma unroll
            for (int ks = 0; ks < 4; ++ks) {
                size_t off = ((size_t)(nt * 4 + ks) * 64 + lane) * 8;
                short8 bh = *(const short8*)(w2h + off);
                short8 bl = *(const short8*)(w2l + off);
                acc = __builtin_amdgcn_mfma_f32_16x16x32_bf16(ch[ks], bh, acc, 0, 0, 0);
                acc = __builtin_amdgcn_mfma_f32_16x16x32_bf16(cl[ks], bh, acc, 0, 0, 0);
                acc = __builtin_amdgcn_mfma_f32_16x16x32_bf16(ch[ks], bl, acc, 0, 0, 0);
            }
            float bv = b2[nt * 16 + m];
#pragma unroll
            for (int r = 0; r < 4; ++r) {
                int rr = m0 + quad * 4 + r;
                float o = acc[r] + bv;
                if (relu2) o = o > 0.f ? o : 0.f;
                if (rr < N) C[(size_t)rr * ND + nt * 16 + m] = o;
                if (xpk) T[(quad * 4 + r) * LP + nt * 16 + m] = o;  // stash
            }
        }

        // ---- fused xprep: pack (C + ben) rows -> xpk granules ----
        if (xpk) {
#pragma unroll
            for (int i = 0; i < 4; ++i) {
                int task = lane + 64 * i;  // 256 tasks = 16 rows x 16 granules
                int rl = task >> 4;
                int g = task & 15;
                int rr = m0 + rl;
                if (rr < N) {
                    const float4* p = (const float4*)(T + rl * LP + g * 8);
                    float4 a0 = p[0], a1 = p[1];
                    float f[8] = {a0.x, a0.y, a0.z, a0.w, a1.x, a1.y, a1.z, a1.w};
                    short8 h, l;
#pragma unroll
                    for (int j = 0; j < 8; ++j) {
                        float fv = f[j] + ben[g * 8 + j];
                        unsigned short hh = bf16_hi(fv);
                        h[j] = (short)hh;
                        l[j] = (short)bf16_hi(fv - bf16_f(hh));
                    }
                    unsigned short* dst = xpk + ((size_t)rr * 16 + g) * 16;
                    *(short8*)dst = h;
                    *(short8*)(dst + 8) = l;
                }
            }
        }
    }
}

__global__ __launch_bounds__(256, 4) void gine_all(GParams P) {
    __shared__ float tile[4][16 * LP];  // 33792 B (mlp phases)
    __shared__ int sred[256];           // 1024 B (scan phases)
    int tid = threadIdx.x;
    int bx = blockIdx.x;
    int g = bx * 256 + tid;
    int N = P.N, E = P.E, NB = P.NB;
    float* T = &tile[threadIdx.x >> 6][0];

    // ================= Phase A: zero | wprep | wprep_we | xprep(layer0) ====
    for (int i = g; i < N; i += GT) P.counts[i] = 0;

    for (int t = g; t < 6 * 2048; t += GT) {  // 6 weight mats -> hi/lo frags
        int y = t >> 11, tt = t & 2047;
        const float* W = (y == 0) ? P.w10 : (y == 1) ? P.w20 : (y == 2) ? P.w11
                       : (y == 3) ? P.w21 : (y == 4) ? P.fc1w : P.fc2w;
        unsigned short* dh = P.wfh + (size_t)y * 16384;
        unsigned short* dl = P.wfl + (size_t)y * 16384;
        int c = tt >> 6, l = tt & 63;
        int nt = c >> 2, ks = c & 3;
        int n = nt * 16 + (l & 15);
        int kb = ks * 32 + ((l >> 4) << 3);
#pragma unroll
        for (int j = 0; j < 8; ++j) {
            float f = W[(size_t)(kb + j) * ND + n];
            unsigned short h = bf16_hi(f);
            dh[((size_t)c * 64 + l) * 8 + j] = h;
            dl[((size_t)c * 64 + l) * 8 + j] = bf16_hi(f - bf16_f(h));
        }
    }

    for (int t = g; t < 2 * 512; t += GT) {  // 2 edge mats -> bf16-hi frags
        int y = t >> 9, idx = t & 511;
        int c = idx >> 6, l = idx & 63;
        const float* W = y ? P.we1 : P.we0;
        unsigned short* dh = P.weh + (size_t)y * 4096;
        int n = c * 16 + (l & 15);
        int kb = (l >> 4) << 3;
#pragma unroll
        for (int j = 0; j < 8; ++j)
            dh[((size_t)c * 64 + l) * 8 + j] = bf16_hi(W[(size_t)(kb + j) * ND + n]);
    }

    for (int t = g; t < (N + 1) * 16; t += GT) {  // xprep: (x+be0) -> xpk
        int v = t >> 4, gg = t & 15;
        short8 h, l;
        if (v < N) {
            const float4* p = (const float4*)(P.x + (size_t)v * ND + gg * 8);
            float4 a0 = p[0], a1 = p[1];
            float f[8] = {a0.x, a0.y, a0.z, a0.w, a1.x, a1.y, a1.z, a1.w};
#pragma unroll
            for (int j = 0; j < 8; ++j) {
                float fv = f[j] + P.be0[gg * 8 + j];
                unsigned short hh = bf16_hi(fv);
                h[j] = (short)hh;
                l[j] = (short)bf16_hi(fv - bf16_f(hh));
            }
        } else {
#pragma unroll
            for (int j = 0; j < 8; ++j) {
                h[j] = (short)0xC6EA;  // bf16(-29958) sentinel
                l[j] = 0;
            }
        }
        unsigned short* dst = P.xpk + (size_t)t * 16;
        *(short8*)dst = h;
        *(short8*)(dst + 8) = l;
    }
    gsync(P.bar, 0);

    // ================= Phase B: hist =======================================
    for (int i = g; i < E; i += GT) atomicAdd(&P.counts[P.ei[E + i]], 1);
    gsync(P.bar, 1);

    // ================= Phase C: per-256-chunk block sums ===================
    for (int b = bx; b < NB; b += GB) {
        int i = b * 256 + tid;
        sred[tid] = (i < N) ? P.counts[i] : 0;
        __syncthreads();
#pragma unroll
        for (int off = 128; off > 0; off >>= 1) {
            if (tid < off) sred[tid] += sred[tid + off];
            __syncthreads();
        }
        if (tid == 0) P.bsum[b] = sred[0];
        __syncthreads();
    }
    gsync(P.bar, 2);

    // ================= Phase D: scan of block sums (block 0) ===============
    if (bx == 0) {
        int chunk = (NB + 255) >> 8;
        int lo = min(tid * chunk, NB);
        int hi = min(lo + chunk, NB);
        int sum = 0;
        for (int i = lo; i < hi; ++i) sum += P.bsum[i];
        sred[tid] = sum;
        __syncthreads();
        for (int off = 1; off < 256; off <<= 1) {
            int v = (tid >= off) ? sred[tid - off] : 0;
            __syncthreads();
            sred[tid] += v;
            __syncthreads();
        }
        int pre = (tid == 0) ? 0 : sred[tid - 1];
        for (int i = lo; i < hi; ++i) {
            P.bofs[i] = pre;
            pre += P.bsum[i];
        }
        if (tid == 255) P.row_start[N] = sred[255];
    }
    gsync(P.bar, 3);

    // ================= Phase E: expand -> row_start/woff ===================
    for (int b = bx; b < NB; b += GB) {
        int i = b * 256 + tid;
        int c = (i < N) ? P.counts[i] : 0;
        sred[tid] = c;
        __syncthreads();
        for (int off = 1; off < 256; off <<= 1) {
            int v = (tid >= off) ? sred[tid - off] : 0;
            __syncthreads();
            sred[tid] += v;
            __syncthreads();
        }
        if (i < N) {
            int pre = P.bofs[b] + sred[tid] - c;  // exclusive
            P.row_start[i] = pre;
            P.woff[i] = pre;
        }
        __syncthreads();
    }
    gsync(P.bar, 4);

    // ================= Phase F: scatter + wave ranges ======================
    for (int i = g; i < E; i += GT) {
        int d = P.ei[E + i];
        int p = atomicAdd(&P.woff[d], 1);
        P.pack[p] = make_int2(P.ei[i], i);  // {src, eid}
    }
    for (int w = g; w <= NWAVES; w += GT) {
        if (w == 0) { P.wstart[0] = 0; continue; }
        if (w == NWAVES) { P.wstart[NWAVES] = N; continue; }
        int Tgt = (int)((long long)w * E / NWAVES);
        int lo = 0, hi = N - 1;
        while (lo < hi) {
            int mid = (lo + hi) >> 1;
            if (P.row_start[mid + 1] > Tgt) hi = mid; else lo = mid + 1;
        }
        P.wstart[w] = lo;
    }
    gsync(P.bar, 5);

    // ================= Phase G..K: the network =============================
    agg_body(P.x, P.ea, P.xpk, P.weh, P.row_start, P.wstart, P.pack, P.out, N, E);
    gsync(P.bar, 6);

    mlp_body(P.out, P.wfh, P.wfl, P.b10, P.wfh + 16384, P.wfl + 16384, P.b20,
             P.bufA, N, 1, P.be1, P.xpk, T);
    gsync(P.bar, 7);

    agg_body(P.bufA, P.ea, P.xpk, P.weh + 4096, P.row_start, P.wstart, P.pack,
             P.out, N, E);
    gsync(P.bar, 8);

    mlp_body(P.out, P.wfh + 2 * 16384, P.wfl + 2 * 16384, P.b11, P.wfh + 3 * 16384,
             P.wfl + 3 * 16384, P.b21, P.bufA, N, 1, nullptr, nullptr, T);
    gsync(P.bar, 9);

    mlp_body(P.bufA, P.wfh + 4 * 16384, P.wfl + 4 * 16384, P.fc1b,
             P.wfh + 5 * 16384, P.wfl + 5 * 16384, P.fc2b, P.out, N, 0,
             nullptr, nullptr, T);
}

extern "C" void kernel_launch(void* const* d_in, const int* in_sizes, int n_in,
                              void* d_out, int out_size, void* d_ws, size_t ws_size,
                              hipStream_t stream) {
    GParams P;
    P.x = (const float*)d_in[0];
    P.ei = (const int*)d_in[1];  // int64 in reference -> int32 from harness
    P.ea = (const float*)d_in[2];
    P.w10 = (const float*)d_in[3];
    P.b10 = (const float*)d_in[4];
    P.w20 = (const float*)d_in[5];
    P.b20 = (const float*)d_in[6];
    P.we0 = (const float*)d_in[7];
    P.be0 = (const float*)d_in[8];
    P.w11 = (const float*)d_in[9];
    P.b11 = (const float*)d_in[10];
    P.w21 = (const float*)d_in[11];
    P.b21 = (const float*)d_in[12];
    P.we1 = (const float*)d_in[13];
    P.be1 = (const float*)d_in[14];
    P.fc1w = (const float*)d_in[15];
    P.fc1b = (const float*)d_in[16];
    P.fc2w = (const float*)d_in[17];
    P.fc2b = (const float*)d_in[18];

    int N = in_sizes[0] / ND;
    int E = in_sizes[2] / ED;
    int NB = (N + 255) / 256;
    P.N = N; P.E = E; P.NB = NB;

    float* bufA = (float*)d_ws;
    int* counts = (int*)(bufA + (size_t)N * ND);
    int* row_start = counts + N;            // N+1
    int* woff = row_start + (N + 1);        // N
    int* bsum = woff + N;                   // NB
    int* bofs = bsum + NB;                  // NB
    int* wstart = bofs + NB;                // NWAVES+1
    int* bar = wstart + (NWAVES + 1);       // 16
    int2* pack = (int2*)((((uintptr_t)(bar + 16)) + 15) & ~(uintptr_t)15);
    unsigned short* wfh = (unsigned short*)(pack + E);
    unsigned short* wfl = wfh + 6 * 16384;
    unsigned short* weh = wfl + 6 * 16384;  // 2 * 4096
    unsigned short* xpk = weh + 2 * 4096;   // (N+1) * 256 ushorts

    P.counts = counts; P.row_start = row_start; P.woff = woff;
    P.bsum = bsum; P.bofs = bofs; P.wstart = wstart; P.bar = bar;
    P.pack = pack; P.wfh = wfh; P.wfl = wfl; P.weh = weh; P.xpk = xpk;
    P.bufA = bufA; P.out = (float*)d_out;

    hipMemsetAsync(bar, 0, 16 * sizeof(int), stream);
    gine_all<<<GB, 256, 0, stream>>>(P);
}

// Round 12
// 500.250 us; speedup vs baseline: 5.6012x; 5.6012x over previous
//
#include <hip/hip_runtime.h>
#include <stdint.h>

// ---------------------------------------------------------------------------
// GINEncoder: 2x GINEConv(eps=0, MLP 128->128->128, edge_lin 32->128) + head.
//   R14 (6th submit; R7-R11 were GPUAcquisitionTimeouts -- never ran).
//   Base: R5 11-launch pipeline (470.5us verified). R6's persistent-kernel
//   regressed 6x (agent-scope spin invalidates per-XCD L2s) -- abandoned.
//   This round targets agg (184us of 470, latency-bound: 92us vs 42us BW
//   floor, pipes 32% busy, 4 waves/SIMD):
//     (a) grid 1024 -> 1536 blocks (NW 6144, ~6 waves/SIMD): R2's thrash was
//         strided assignment at 8 waves; contiguous ranges keep streams local.
//     (b) one-chunk-ahead ea prefetch via pk2.y (pack already 1-ahead);
//         pad-lane ea garbage is killed by the x-sentinel relu, same as pack.
//   Everything else verbatim R5: prepwx merge, scatter_wrange merge, fused
//   xprep1 in mlp0, agg identity-B x-gather + bf16 hi/lo exact math.
// edge_index is int64 in the reference but harness passes int32.
// ---------------------------------------------------------------------------

#define ND 128
#define ED 32

typedef __attribute__((ext_vector_type(8))) short short8;
typedef __attribute__((ext_vector_type(4))) float f32x4;

__device__ inline unsigned short bf16_hi(float f) {
    union { float f; unsigned u; } v;
    v.f = f;
    return (unsigned short)(v.u >> 16);  // truncation; residual captured by lo
}
__device__ inline float bf16_f(unsigned short h) {
    union { unsigned u; float f; } v;
    v.u = ((unsigned)h) << 16;
    return v.f;
}

__global__ __launch_bounds__(256) void hist_kernel(const int* __restrict__ ei,
                                                   int* __restrict__ counts, int E) {
    int i = blockIdx.x * blockDim.x + threadIdx.x;
    if (i < E) atomicAdd(&counts[ei[E + i]], 1);
}

// ---- two-level parallel scan over counts[N] ----
__global__ __launch_bounds__(256) void bsum_kernel(const int* __restrict__ counts,
                                                   int* __restrict__ bsum, int N) {
    __shared__ int s[256];
    int t = threadIdx.x;
    int i = blockIdx.x * 256 + t;
    s[t] = (i < N) ? counts[i] : 0;
    __syncthreads();
#pragma unroll
    for (int off = 128; off > 0; off >>= 1) {
        if (t < off) s[t] += s[t + off];
        __syncthreads();
    }
    if (t == 0) bsum[blockIdx.x] = s[0];
}

__global__ __launch_bounds__(256) void scan_bsums(const int* __restrict__ bsum,
                                                  int* __restrict__ bofs,
                                                  int* __restrict__ row_start_N, int NB) {
    __shared__ int s[256];
    int t = threadIdx.x;
    int chunk = (NB + 255) >> 8;
    int lo = min(t * chunk, NB);
    int hi = min(lo + chunk, NB);
    int sum = 0;
    for (int i = lo; i < hi; ++i) sum += bsum[i];
    s[t] = sum;
    __syncthreads();
    for (int off = 1; off < 256; off <<= 1) {
        int v = (t >= off) ? s[t - off] : 0;
        __syncthreads();
        s[t] += v;
        __syncthreads();
    }
    int pre = (t == 0) ? 0 : s[t - 1];
    for (int i = lo; i < hi; ++i) {
        bofs[i] = pre;
        pre += bsum[i];
    }
    if (t == 255) *row_start_N = s[255];
}

__global__ __launch_bounds__(256) void expand_kernel(const int* __restrict__ counts,
                                                     const int* __restrict__ bofs,
                                                     int* __restrict__ row_start,
                                                     int* __restrict__ woff, int N) {
    __shared__ int s[256];
    int t = threadIdx.x;
    int i = blockIdx.x * 256 + t;
    int c = (i < N) ? counts[i] : 0;
    s[t] = c;
    __syncthreads();
    for (int off = 1; off < 256; off <<= 1) {
        int v = (t >= off) ? s[t - off] : 0;
        __syncthreads();
        s[t] += v;
        __syncthreads();
    }
    if (i < N) {
        int pre = bofs[blockIdx.x] + s[t] - c;  // exclusive
        row_start[i] = pre;
        woff[i] = pre;
    }
}

// scatter (blocks [0,SB)) + edge-balanced wave ranges (blocks [SB, SB+WB)).
// wstart[w] = min v : row_start[v+1] > w*E/NW  (forced 0 at w=0, N at w=NW).
__global__ __launch_bounds__(256) void scatter_wrange(
    const int* __restrict__ ei, int* __restrict__ woff, int2* __restrict__ pack,
    int E, const int* __restrict__ row_start, int* __restrict__ wstart,
    int N, int NW) {
    int b = blockIdx.x;
    int SB = (E + 255) >> 8;
    if (b < SB) {
        int i = b * 256 + threadIdx.x;
        if (i < E) {
            int d = ei[E + i];
            int p = atomicAdd(&woff[d], 1);
            pack[p] = make_int2(ei[i], i);  // {src, eid}
        }
        return;
    }
    int w = (b - SB) * 256 + threadIdx.x;
    if (w > NW) return;
    if (w == 0) { wstart[0] = 0; return; }
    if (w == NW) { wstart[NW] = N; return; }
    int T = (int)((long long)w * E / NW);
    int lo = 0, hi = N - 1;
    while (lo < hi) {
        int mid = (lo + hi) >> 1;
        if (row_start[mid + 1] > T) hi = mid; else lo = mid + 1;
    }
    wstart[w] = lo;
}

// Merged prep: zero(counts) + wprep(6 weight mats -> bf16 hi/lo B-fragments)
// + wprep_we(2 edge mats -> bf16-hi B-fragments) + xprep(x + be_0 -> xpk).
// Role by linear blockIdx.x ranges.
__global__ __launch_bounds__(256) void prepwx_kernel(
    int* __restrict__ counts, int N,
    const float* __restrict__ w0, const float* __restrict__ w1,
    const float* __restrict__ w2, const float* __restrict__ w3,
    const float* __restrict__ w4, const float* __restrict__ w5,
    unsigned short* __restrict__ hi, unsigned short* __restrict__ lo,
    const float* __restrict__ e0, const float* __restrict__ e1,
    unsigned short* __restrict__ weh,
    const float* __restrict__ X, const float* __restrict__ be,
    unsigned short* __restrict__ xpk) {
    int b = blockIdx.x;
    int ZB = (N + 255) >> 8;
    if (b < ZB) {  // ---- zero counts ----
        int i = b * 256 + threadIdx.x;
        if (i < N) counts[i] = 0;
        return;
    }
    b -= ZB;
    if (b < 48) {  // ---- wprep: matrix y=b/8, t in [0,2048) ----
        int y = b >> 3;
        int t = (b & 7) * 256 + threadIdx.x;
        const float* W;
        switch (y) {
            case 0: W = w0; break;
            case 1: W = w1; break;
            case 2: W = w2; break;
            case 3: W = w3; break;
            case 4: W = w4; break;
            default: W = w5; break;
        }
        unsigned short* dh = hi + (size_t)y * 16384;
        unsigned short* dl = lo + (size_t)y * 16384;
        int c = t >> 6, l = t & 63;
        int nt = c >> 2, ks = c & 3;
        int n = nt * 16 + (l & 15);
        int kb = ks * 32 + ((l >> 4) << 3);
#pragma unroll
        for (int j = 0; j < 8; ++j) {
            float f = W[(size_t)(kb + j) * ND + n];
            unsigned short h = bf16_hi(f);
            dh[((size_t)c * 64 + l) * 8 + j] = h;
            dl[((size_t)c * 64 + l) * 8 + j] = bf16_hi(f - bf16_f(h));
        }
        return;
    }
    b -= 48;
    if (b < 4) {  // ---- wprep_we: xb=b&1, mat y=b>>1 ----
        int t = threadIdx.x;
        int c = ((b & 1) << 2) + (t >> 6);  // nt 0..7
        int l = t & 63;
        const float* W = (b >> 1) ? e1 : e0;
        unsigned short* dh = weh + (size_t)(b >> 1) * 4096;
        int n = c * 16 + (l & 15);
        int kb = (l >> 4) << 3;
#pragma unroll
        for (int j = 0; j < 8; ++j)
            dh[((size_t)c * 64 + l) * 8 + j] = bf16_hi(W[(size_t)(kb + j) * ND + n]);
        return;
    }
    b -= 4;
    // ---- xprep role: pack (X + be) -> xpk, plus sentinel row N ----
    int t = b * 256 + threadIdx.x;
    int total = (N + 1) * 16;
    if (t >= total) return;
    int v = t >> 4, g = t & 15;
    short8 h, l;
    if (v < N) {
        const float4* p = (const float4*)(X + (size_t)v * ND + g * 8);
        float4 a0 = p[0], a1 = p[1];
        float f[8] = {a0.x, a0.y, a0.z, a0.w, a1.x, a1.y, a1.z, a1.w};
#pragma unroll
        for (int j = 0; j < 8; ++j) {
            float fv = f[j] + be[g * 8 + j];
            unsigned short hh = bf16_hi(fv);
            h[j] = (short)hh;
            l[j] = (short)bf16_hi(fv - bf16_f(hh));
        }
    } else {
#pragma unroll
        for (int j = 0; j < 8; ++j) {
            h[j] = (short)0xC6EA;  // bf16(-29958)
            l[j] = 0;
        }
    }
    unsigned short* dst = xpk + (size_t)t * 16;
    *(short8*)dst = h;
    *(short8*)(dst + 8) = l;
}

// Node-centric MFMA aggregation over a contiguous, edge-balanced node range.
// h[v] = x[v] + sum_{e: dst=v} relu((x[src_e]+be) + ea_e @ we)
// R14: pack 1-ahead (R3) AND ea 1-ahead via pk2.y; pad-lane ea garbage is
// neutralized by the x-sentinel relu.
__global__ __launch_bounds__(256, 4) void agg_mfma(
    const float* __restrict__ xin, const float* __restrict__ edge_attr,
    const unsigned short* __restrict__ xpk, const unsigned short* __restrict__ bfh,
    const int* __restrict__ row_start, const int* __restrict__ wstart,
    const int2* __restrict__ pack, float* __restrict__ hout, int N, int E) {
    int lane = threadIdx.x & 63;
    int gw = (blockIdx.x * blockDim.x + threadIdx.x) >> 6;
    int m = lane & 15;
    int quad = lane >> 4;

    // we fragments (bf16-hi), held in registers for the whole kernel
    short8 bh[8];
#pragma unroll
    for (int nt = 0; nt < 8; ++nt)
        bh[nt] = *(const short8*)(bfh + ((size_t)nt * 64 + lane) * 8);

    // identity B-fragments: for tile parity q, B[k'=quad*8+j][n'=m] = (k'==q*16+m)
    short8 idf[2];
#pragma unroll
    for (int q = 0; q < 2; ++q)
#pragma unroll
        for (int j = 0; j < 8; ++j)
            idf[q][j] = (quad * 8 + j == q * 16 + m) ? (short)0x3F80 : (short)0;

    int col0 = quad * 32 + m;
    int col1 = col0 + 16;

    int v_lo = wstart[gw];
    int v_hi = wstart[gw + 1];
    if (v_lo >= v_hi) return;

    int beg = row_start[v_lo];
    // pack prefetch (1 chunk ahead) + ea prefetch (1 chunk ahead via pk2.y)
    int2 pk2 = pack[min(beg + m, E - 1)];
    const float4* ar0 = (const float4*)(edge_attr + (size_t)pk2.y * ED + quad * 8);
    float4 ea0p = ar0[0], ea1p = ar0[1];

    for (int v = v_lo; v < v_hi; ++v) {
        int end = row_start[v + 1];
        // residual loads overlap the gather latency below
        float res0 = xin[(size_t)v * ND + col0];
        float res1 = xin[(size_t)v * ND + col1];
        float part[8];
#pragma unroll
        for (int nt = 0; nt < 8; ++nt) part[nt] = 0.f;

        for (int base = beg; base < end; base += 16) {
            int2 pk = pk2;
            float4 a0 = ea0p, a1 = ea1p;  // this chunk's ea (prefetched)
            // next chunk: same node (base+16) or next node's first chunk (end)
            int nxt = (base + 16 < end) ? base + 16 : end;
            pk2 = pack[min(nxt + m, E - 1)];

            int rem = end - base;  // >= 1
            int s = (m < rem) ? pk.x : N;  // sentinel row kills pad lanes in relu

            // ---- batched loads: 8 dwordx4 x-fragments ----
            const unsigned short* xr = xpk + ((size_t)s * 16 + quad) * 16;
            short8 xh[4], xl[4];
#pragma unroll
            for (int kc = 0; kc < 4; ++kc) {
                xh[kc] = *(const short8*)(xr + kc * 64);
                xl[kc] = *(const short8*)(xr + kc * 64 + 8);
            }

            // ---- issue next chunk's ea prefetch (pk2 back by now: issued
            // above, ~L2 latency covered by xpk gather issue + addr VALU) ----
            const float4* arn =
                (const float4*)(edge_attr + (size_t)pk2.y * ED + quad * 8);
            ea0p = arn[0];
            ea1p = arn[1];

            // ea A-fragment split hi/lo (exact)
            float af[8] = {a0.x, a0.y, a0.z, a0.w, a1.x, a1.y, a1.z, a1.w};
            short8 ah, al;
#pragma unroll
            for (int j = 0; j < 8; ++j) {
                unsigned short h = bf16_hi(af[j]);
                ah[j] = (short)h;
                al[j] = (short)bf16_hi(af[j] - bf16_f(h));
            }

#pragma unroll
            for (int nt = 0; nt < 8; ++nt) {
                f32x4 a = {0.f, 0.f, 0.f, 0.f};
                a = __builtin_amdgcn_mfma_f32_16x16x32_bf16(ah, bh[nt], a, 0, 0, 0);
                a = __builtin_amdgcn_mfma_f32_16x16x32_bf16(al, bh[nt], a, 0, 0, 0);
                a = __builtin_amdgcn_mfma_f32_16x16x32_bf16(xh[nt >> 1], idf[nt & 1], a,
                                                            0, 0, 0);
                a = __builtin_amdgcn_mfma_f32_16x16x32_bf16(xl[nt >> 1], idf[nt & 1], a,
                                                            0, 0, 0);
#pragma unroll
                for (int r = 0; r < 4; ++r)
                    part[nt] += fmaxf(a[r], 0.f);  // be already inside xpk
            }
        }
        // reduce over quads (cols live in lanes m, m+16, m+32, m+48)
#pragma unroll
        for (int nt = 0; nt < 8; ++nt) {
            float p = part[nt];
            p += __shfl_xor(p, 16, 64);
            p += __shfl_xor(p, 32, 64);
            part[nt] = p;
        }
        // quad q writes cols of tiles 2q, 2q+1
        float o0 = quad == 0 ? part[0] : quad == 1 ? part[2] : quad == 2 ? part[4] : part[6];
        float o1 = quad == 0 ? part[1] : quad == 1 ? part[3] : quad == 2 ? part[5] : part[7];
        hout[(size_t)v * ND + col0] = res0 + o0;
        hout[(size_t)v * ND + col1] = res1 + o1;
        beg = end;
    }
}

// Fused pair of GEMMs: C = maybe_relu2( relu(A@W1+b1) @ W2 + b2 ).
// Wave = 16 rows; intermediate goes through a per-wave LDS tile (132-pad rows).
// If xpk != nullptr, also emits xpk fragments of (C + ben) via the (dead by
// then) LDS tile -- fuses the next layer's xprep pass into this kernel.
#define LP 132  // padded LDS row stride (floats); 132*4B keeps 16B alignment
__global__ __launch_bounds__(256, 4) void mlp2_mfma(
    const float* __restrict__ A,
    const unsigned short* __restrict__ w1h, const unsigned short* __restrict__ w1l,
    const float* __restrict__ b1,
    const unsigned short* __restrict__ w2h, const unsigned short* __restrict__ w2l,
    const float* __restrict__ b2,
    float* __restrict__ C, int N, int relu2,
    const float* __restrict__ ben, unsigned short* __restrict__ xpk) {
    __shared__ float tile[4][16 * LP];
    int lane = threadIdx.x & 63;
    int wave = threadIdx.x >> 6;
    int gw = blockIdx.x * 4 + wave;
    int m0 = gw * 16;
    if (m0 >= N) return;
    int m = lane & 15;
    int quad = lane >> 4;
    float* T = tile[wave];

    // ---- stage 1: load A rows, split hi/lo ----
    int row = m0 + m;
    bool rok = row < N;
    short8 ah[4], al[4];
#pragma unroll
    for (int ks = 0; ks < 4; ++ks) {
        float f[8];
        if (rok) {
            const float4* p = (const float4*)(A + (size_t)row * ND + ks * 32 + quad * 8);
            float4 a0 = p[0], a1 = p[1];
            f[0] = a0.x; f[1] = a0.y; f[2] = a0.z; f[3] = a0.w;
            f[4] = a1.x; f[5] = a1.y; f[6] = a1.z; f[7] = a1.w;
        } else {
#pragma unroll
            for (int j = 0; j < 8; ++j) f[j] = 0.f;
        }
#pragma unroll
        for (int j = 0; j < 8; ++j) {
            unsigned short hh = bf16_hi(f[j]);
            ah[ks][j] = (short)hh;
            al[ks][j] = (short)bf16_hi(f[j] - bf16_f(hh));
        }
    }

    // GEMM1 -> bias + relu -> LDS tile (C/D layout: col=lane&15, row=quad*4+r)
#pragma unroll
    for (int nt = 0; nt < 8; ++nt) {
        f32x4 acc = {0.f, 0.f, 0.f, 0.f};
#pragma unroll
        for (int ks = 0; ks < 4; ++ks) {
            size_t off = ((size_t)(nt * 4 + ks) * 64 + lane) * 8;
            short8 bh = *(const short8*)(w1h + off);
            short8 bl = *(const short8*)(w1l + off);
            acc = __builtin_amdgcn_mfma_f32_16x16x32_bf16(ah[ks], bh, acc, 0, 0, 0);
            acc = __builtin_amdgcn_mfma_f32_16x16x32_bf16(al[ks], bh, acc, 0, 0, 0);
            acc = __builtin_amdgcn_mfma_f32_16x16x32_bf16(ah[ks], bl, acc, 0, 0, 0);
        }
        float bv = b1[nt * 16 + m];
#pragma unroll
        for (int r = 0; r < 4; ++r) {
            float o = acc[r] + bv;
            o = o > 0.f ? o : 0.f;
            T[(quad * 4 + r) * LP + nt * 16 + m] = o;
        }
    }

    // ---- stage 2: rows from LDS as A-fragments (same wave -> lgkmcnt wait) ----
    short8 ch[4], cl[4];
#pragma unroll
    for (int ks = 0; ks < 4; ++ks) {
        const float4* p = (const float4*)(T + m * LP + ks * 32 + quad * 8);
        float4 a0 = p[0], a1 = p[1];
        float f[8] = {a0.x, a0.y, a0.z, a0.w, a1.x, a1.y, a1.z, a1.w};
#pragma unroll
        for (int j = 0; j < 8; ++j) {
            unsigned short hh = bf16_hi(f[j]);
            ch[ks][j] = (short)hh;
            cl[ks][j] = (short)bf16_hi(f[j] - bf16_f(hh));
        }
    }

#pragma unroll
    for (int nt = 0; nt < 8; ++nt) {
        f32x4 acc = {0.f, 0.f, 0.f, 0.f};
#pragma unroll
        for (int ks = 0; ks < 4; ++ks) {
            size_t off = ((size_t)(nt * 4 + ks) * 64 + lane) * 8;
            short8 bh = *(const short8*)(w2h + off);
            short8 bl = *(const short8*)(w2l + off);
            acc = __builtin_amdgcn_mfma_f32_16x16x32_bf16(ch[ks], bh, acc, 0, 0, 0);
            acc = __builtin_amdgcn_mfma_f32_16x16x32_bf16(cl[ks], bh, acc, 0, 0, 0);
            acc = __builtin_amdgcn_mfma_f32_16x16x32_bf16(ch[ks], bl, acc, 0, 0, 0);
        }
        float bv = b2[nt * 16 + m];
#pragma unroll
        for (int r = 0; r < 4; ++r) {
            int rr = m0 + quad * 4 + r;
            float o = acc[r] + bv;
            if (relu2) o = o > 0.f ? o : 0.f;
            if (rr < N) C[(size_t)rr * ND + nt * 16 + m] = o;
            if (xpk) T[(quad * 4 + r) * LP + nt * 16 + m] = o;  // stash for pack
        }
    }

    // ---- fused xprep: pack (C + ben) rows -> xpk granules ----
    if (xpk) {
#pragma unroll
        for (int i = 0; i < 4; ++i) {
            int task = lane + 64 * i;  // 256 tasks = 16 rows x 16 granules
            int rl = task >> 4;
            int g = task & 15;
            int rr = m0 + rl;
            if (rr < N) {
                const float4* p = (const float4*)(T + rl * LP + g * 8);
                float4 a0 = p[0], a1 = p[1];
                float f[8] = {a0.x, a0.y, a0.z, a0.w, a1.x, a1.y, a1.z, a1.w};
                short8 h, l;
#pragma unroll
                for (int j = 0; j < 8; ++j) {
                    float fv = f[j] + ben[g * 8 + j];
                    unsigned short hh = bf16_hi(fv);
                    h[j] = (short)hh;
                    l[j] = (short)bf16_hi(fv - bf16_f(hh));
                }
                unsigned short* dst = xpk + ((size_t)rr * 16 + g) * 16;
                *(short8*)dst = h;
                *(short8*)(dst + 8) = l;
            }
        }
    }
}

extern "C" void kernel_launch(void* const* d_in, const int* in_sizes, int n_in,
                              void* d_out, int out_size, void* d_ws, size_t ws_size,
                              hipStream_t stream) {
    const float* x = (const float*)d_in[0];
    const int* ei = (const int*)d_in[1];  // int64 in reference -> int32 from harness
    const float* ea = (const float*)d_in[2];
    const float* w1_0 = (const float*)d_in[3];
    const float* b1_0 = (const float*)d_in[4];
    const float* w2_0 = (const float*)d_in[5];
    const float* b2_0 = (const float*)d_in[6];
    const float* we_0 = (const float*)d_in[7];
    const float* be_0 = (const float*)d_in[8];
    const float* w1_1 = (const float*)d_in[9];
    const float* b1_1 = (const float*)d_in[10];
    const float* w2_1 = (const float*)d_in[11];
    const float* b2_1 = (const float*)d_in[12];
    const float* we_1 = (const float*)d_in[13];
    const float* be_1 = (const float*)d_in[14];
    const float* fc1_w = (const float*)d_in[15];
    const float* fc1_b = (const float*)d_in[16];
    const float* fc2_w = (const float*)d_in[17];
    const float* fc2_b = (const float*)d_in[18];

    int N = in_sizes[0] / ND;
    int E = in_sizes[2] / ED;
    int NB = (N + 255) / 256;
    const int NW = 6144;  // agg waves (1536 blocks = 6 blocks/CU, 6 waves/SIMD)

    float* bufA = (float*)d_ws;
    int* counts = (int*)(bufA + (size_t)N * ND);
    int* row_start = counts + N;        // N+1
    int* woff = row_start + (N + 1);    // N
    int* bsum = woff + N;               // NB
    int* bofs = bsum + NB;              // NB
    int* wstart = bofs + NB;            // NW+1
    int2* pack = (int2*)((((uintptr_t)(wstart + NW + 1)) + 15) & ~(uintptr_t)15);
    unsigned short* wfh = (unsigned short*)(pack + E);
    unsigned short* wfl = wfh + 6 * 16384;
    unsigned short* weh = wfl + 6 * 16384;  // 2 * 4096
    unsigned short* xpk = weh + 2 * 4096;   // (N+1) * 256 ushorts = 512B/row
    float* out = (float*)d_out;

    int ZB = (N + 255) / 256;
    int gx = ((N + 1) * 16 + 255) / 256;   // xprep role blocks
    int SB = (E + 255) / 256;              // scatter role blocks
    int WB = (NW + 1 + 255) / 256;         // wrange role blocks
    int gg = ((N + 15) / 16 + 3) / 4;      // fused-MLP blocks (4 waves x 16 rows)

    // ---- prep: 6 launches ----
    prepwx_kernel<<<ZB + 48 + 4 + gx, 256, 0, stream>>>(
        counts, N, w1_0, w2_0, w1_1, w2_1, fc1_w, fc2_w, wfh, wfl,
        we_0, we_1, weh, x, be_0, xpk);
    hist_kernel<<<(E + 255) / 256, 256, 0, stream>>>(ei, counts, E);
    bsum_kernel<<<NB, 256, 0, stream>>>(counts, bsum, N);
    scan_bsums<<<1, 256, 0, stream>>>(bsum, bofs, row_start + N, NB);
    expand_kernel<<<NB, 256, 0, stream>>>(counts, bofs, row_start, woff, N);
    scatter_wrange<<<SB + WB, 256, 0, stream>>>(ei, woff, pack, E, row_start, wstart,
                                                N, NW);

    // ---- layer 0 ----  agg0: x -> out; mlp0: out -> bufA (+ xpk for layer 1)
    agg_mfma<<<NW / 4, 256, 0, stream>>>(x, ea, xpk, weh, row_start, wstart, pack, out,
                                         N, E);
    mlp2_mfma<<<gg, 256, 0, stream>>>(out, wfh + 0 * 16384, wfl + 0 * 16384, b1_0,
                                      wfh + 1 * 16384, wfl + 1 * 16384, b2_0, bufA, N, 1,
                                      be_1, xpk);

    // ---- layer 1 ----  agg1: bufA -> out; mlp1: out -> bufA
    agg_mfma<<<NW / 4, 256, 0, stream>>>(bufA, ea, xpk, weh + 4096, row_start, wstart,
                                         pack, out, N, E);
    mlp2_mfma<<<gg, 256, 0, stream>>>(out, wfh + 2 * 16384, wfl + 2 * 16384, b1_1,
                                      wfh + 3 * 16384, wfl + 3 * 16384, b2_1, bufA, N, 1,
                                      nullptr, nullptr);

    // ---- head ----  bufA -> out (final)
    mlp2_mfma<<<gg, 256, 0, stream>>>(bufA, wfh + 4 * 16384, wfl + 4 * 16384, fc1_b,
                                      wfh + 5 * 16384, wfl + 5 * 16384, fc2_b, out, N, 0,
                                      nullptr, nullptr);
}

// Round 13
// 472.010 us; speedup vs baseline: 5.9363x; 1.0598x over previous
//
#include <hip/hip_runtime.h>
#include <stdint.h>

// ---------------------------------------------------------------------------
// GINEncoder: 2x GINEConv(eps=0, MLP 128->128->128, edge_lin 32->128) + head.
//   R16: R12's A/B (grid 1536 + chained ea-prefetch) regressed agg 92->112us
//   with FLAT FETCH/WRITE -> not L2 thrash. Diagnosis: (1) ea-prefetch chained
//   off pk2 forces a mid-iteration vmcnt wait (serializes each chunk's memory
//   phase); (2) 1536 blocks leaves a 512-block residency tail. This round
//   isolates pure TLP: agg body reverted to the EXACT R5 form (pack-prefetch
//   only, 92us verified), grid 1024 -> 2048 blocks (NW 8192 = 8 blocks/CU
//   exactly; VGPR=64 -> 8 waves/SIMD fits the 512-VGPR budget; no tail).
//   R12 proved contiguous edge-balanced ranges keep FETCH flat at high
//   concurrency (R2's thrash was strided-assignment-specific).
//   Everything else verbatim R5: prepwx merge, scatter_wrange merge, fused
//   xprep1 in mlp0, agg identity-B x-gather + bf16 hi/lo exact math.
// edge_index is int64 in the reference but harness passes int32.
// ---------------------------------------------------------------------------

#define ND 128
#define ED 32

typedef __attribute__((ext_vector_type(8))) short short8;
typedef __attribute__((ext_vector_type(4))) float f32x4;

__device__ inline unsigned short bf16_hi(float f) {
    union { float f; unsigned u; } v;
    v.f = f;
    return (unsigned short)(v.u >> 16);  // truncation; residual captured by lo
}
__device__ inline float bf16_f(unsigned short h) {
    union { unsigned u; float f; } v;
    v.u = ((unsigned)h) << 16;
    return v.f;
}

__global__ __launch_bounds__(256) void hist_kernel(const int* __restrict__ ei,
                                                   int* __restrict__ counts, int E) {
    int i = blockIdx.x * blockDim.x + threadIdx.x;
    if (i < E) atomicAdd(&counts[ei[E + i]], 1);
}

// ---- two-level parallel scan over counts[N] ----
__global__ __launch_bounds__(256) void bsum_kernel(const int* __restrict__ counts,
                                                   int* __restrict__ bsum, int N) {
    __shared__ int s[256];
    int t = threadIdx.x;
    int i = blockIdx.x * 256 + t;
    s[t] = (i < N) ? counts[i] : 0;
    __syncthreads();
#pragma unroll
    for (int off = 128; off > 0; off >>= 1) {
        if (t < off) s[t] += s[t + off];
        __syncthreads();
    }
    if (t == 0) bsum[blockIdx.x] = s[0];
}

__global__ __launch_bounds__(256) void scan_bsums(const int* __restrict__ bsum,
                                                  int* __restrict__ bofs,
                                                  int* __restrict__ row_start_N, int NB) {
    __shared__ int s[256];
    int t = threadIdx.x;
    int chunk = (NB + 255) >> 8;
    int lo = min(t * chunk, NB);
    int hi = min(lo + chunk, NB);
    int sum = 0;
    for (int i = lo; i < hi; ++i) sum += bsum[i];
    s[t] = sum;
    __syncthreads();
    for (int off = 1; off < 256; off <<= 1) {
        int v = (t >= off) ? s[t - off] : 0;
        __syncthreads();
        s[t] += v;
        __syncthreads();
    }
    int pre = (t == 0) ? 0 : s[t - 1];
    for (int i = lo; i < hi; ++i) {
        bofs[i] = pre;
        pre += bsum[i];
    }
    if (t == 255) *row_start_N = s[255];
}

__global__ __launch_bounds__(256) void expand_kernel(const int* __restrict__ counts,
                                                     const int* __restrict__ bofs,
                                                     int* __restrict__ row_start,
                                                     int* __restrict__ woff, int N) {
    __shared__ int s[256];
    int t = threadIdx.x;
    int i = blockIdx.x * 256 + t;
    int c = (i < N) ? counts[i] : 0;
    s[t] = c;
    __syncthreads();
    for (int off = 1; off < 256; off <<= 1) {
        int v = (t >= off) ? s[t - off] : 0;
        __syncthreads();
        s[t] += v;
        __syncthreads();
    }
    if (i < N) {
        int pre = bofs[blockIdx.x] + s[t] - c;  // exclusive
        row_start[i] = pre;
        woff[i] = pre;
    }
}

// scatter (blocks [0,SB)) + edge-balanced wave ranges (blocks [SB, SB+WB)).
// wstart[w] = min v : row_start[v+1] > w*E/NW  (forced 0 at w=0, N at w=NW).
__global__ __launch_bounds__(256) void scatter_wrange(
    const int* __restrict__ ei, int* __restrict__ woff, int2* __restrict__ pack,
    int E, const int* __restrict__ row_start, int* __restrict__ wstart,
    int N, int NW) {
    int b = blockIdx.x;
    int SB = (E + 255) >> 8;
    if (b < SB) {
        int i = b * 256 + threadIdx.x;
        if (i < E) {
            int d = ei[E + i];
            int p = atomicAdd(&woff[d], 1);
            pack[p] = make_int2(ei[i], i);  // {src, eid}
        }
        return;
    }
    int w = (b - SB) * 256 + threadIdx.x;
    if (w > NW) return;
    if (w == 0) { wstart[0] = 0; return; }
    if (w == NW) { wstart[NW] = N; return; }
    int T = (int)((long long)w * E / NW);
    int lo = 0, hi = N - 1;
    while (lo < hi) {
        int mid = (lo + hi) >> 1;
        if (row_start[mid + 1] > T) hi = mid; else lo = mid + 1;
    }
    wstart[w] = lo;
}

// Merged prep: zero(counts) + wprep(6 weight mats -> bf16 hi/lo B-fragments)
// + wprep_we(2 edge mats -> bf16-hi B-fragments) + xprep(x + be_0 -> xpk).
// Role by linear blockIdx.x ranges.
__global__ __launch_bounds__(256) void prepwx_kernel(
    int* __restrict__ counts, int N,
    const float* __restrict__ w0, const float* __restrict__ w1,
    const float* __restrict__ w2, const float* __restrict__ w3,
    const float* __restrict__ w4, const float* __restrict__ w5,
    unsigned short* __restrict__ hi, unsigned short* __restrict__ lo,
    const float* __restrict__ e0, const float* __restrict__ e1,
    unsigned short* __restrict__ weh,
    const float* __restrict__ X, const float* __restrict__ be,
    unsigned short* __restrict__ xpk) {
    int b = blockIdx.x;
    int ZB = (N + 255) >> 8;
    if (b < ZB) {  // ---- zero counts ----
        int i = b * 256 + threadIdx.x;
        if (i < N) counts[i] = 0;
        return;
    }
    b -= ZB;
    if (b < 48) {  // ---- wprep: matrix y=b/8, t in [0,2048) ----
        int y = b >> 3;
        int t = (b & 7) * 256 + threadIdx.x;
        const float* W;
        switch (y) {
            case 0: W = w0; break;
            case 1: W = w1; break;
            case 2: W = w2; break;
            case 3: W = w3; break;
            case 4: W = w4; break;
            default: W = w5; break;
        }
        unsigned short* dh = hi + (size_t)y * 16384;
        unsigned short* dl = lo + (size_t)y * 16384;
        int c = t >> 6, l = t & 63;
        int nt = c >> 2, ks = c & 3;
        int n = nt * 16 + (l & 15);
        int kb = ks * 32 + ((l >> 4) << 3);
#pragma unroll
        for (int j = 0; j < 8; ++j) {
            float f = W[(size_t)(kb + j) * ND + n];
            unsigned short h = bf16_hi(f);
            dh[((size_t)c * 64 + l) * 8 + j] = h;
            dl[((size_t)c * 64 + l) * 8 + j] = bf16_hi(f - bf16_f(h));
        }
        return;
    }
    b -= 48;
    if (b < 4) {  // ---- wprep_we: xb=b&1, mat y=b>>1 ----
        int t = threadIdx.x;
        int c = ((b & 1) << 2) + (t >> 6);  // nt 0..7
        int l = t & 63;
        const float* W = (b >> 1) ? e1 : e0;
        unsigned short* dh = weh + (size_t)(b >> 1) * 4096;
        int n = c * 16 + (l & 15);
        int kb = (l >> 4) << 3;
#pragma unroll
        for (int j = 0; j < 8; ++j)
            dh[((size_t)c * 64 + l) * 8 + j] = bf16_hi(W[(size_t)(kb + j) * ND + n]);
        return;
    }
    b -= 4;
    // ---- xprep role: pack (X + be) -> xpk, plus sentinel row N ----
    int t = b * 256 + threadIdx.x;
    int total = (N + 1) * 16;
    if (t >= total) return;
    int v = t >> 4, g = t & 15;
    short8 h, l;
    if (v < N) {
        const float4* p = (const float4*)(X + (size_t)v * ND + g * 8);
        float4 a0 = p[0], a1 = p[1];
        float f[8] = {a0.x, a0.y, a0.z, a0.w, a1.x, a1.y, a1.z, a1.w};
#pragma unroll
        for (int j = 0; j < 8; ++j) {
            float fv = f[j] + be[g * 8 + j];
            unsigned short hh = bf16_hi(fv);
            h[j] = (short)hh;
            l[j] = (short)bf16_hi(fv - bf16_f(hh));
        }
    } else {
#pragma unroll
        for (int j = 0; j < 8; ++j) {
            h[j] = (short)0xC6EA;  // bf16(-29958)
            l[j] = 0;
        }
    }
    unsigned short* dst = xpk + (size_t)t * 16;
    *(short8*)dst = h;
    *(short8*)(dst + 8) = l;
}

// Node-centric MFMA aggregation over a contiguous, edge-balanced node range.
// h[v] = x[v] + sum_{e: dst=v} relu((x[src_e]+be) + ea_e @ we)
// Body is the verified R5/R3 form (pack 1-ahead only; ea loaded from pk.y
// already in-register -- NO chained ea prefetch, R12 showed it serializes).
__global__ __launch_bounds__(256, 4) void agg_mfma(
    const float* __restrict__ xin, const float* __restrict__ edge_attr,
    const unsigned short* __restrict__ xpk, const unsigned short* __restrict__ bfh,
    const int* __restrict__ row_start, const int* __restrict__ wstart,
    const int2* __restrict__ pack, float* __restrict__ hout, int N, int E) {
    int lane = threadIdx.x & 63;
    int gw = (blockIdx.x * blockDim.x + threadIdx.x) >> 6;
    int m = lane & 15;
    int quad = lane >> 4;

    // we fragments (bf16-hi), held in registers for the whole kernel
    short8 bh[8];
#pragma unroll
    for (int nt = 0; nt < 8; ++nt)
        bh[nt] = *(const short8*)(bfh + ((size_t)nt * 64 + lane) * 8);

    // identity B-fragments: for tile parity q, B[k'=quad*8+j][n'=m] = (k'==q*16+m)
    short8 idf[2];
#pragma unroll
    for (int q = 0; q < 2; ++q)
#pragma unroll
        for (int j = 0; j < 8; ++j)
            idf[q][j] = (quad * 8 + j == q * 16 + m) ? (short)0x3F80 : (short)0;

    int col0 = quad * 32 + m;
    int col1 = col0 + 16;

    int v_lo = wstart[gw];
    int v_hi = wstart[gw + 1];
    if (v_lo >= v_hi) return;

    int beg = row_start[v_lo];
    // pack prefetch: pk2 always holds entries for the next chunk position.
    int2 pk2 = pack[min(beg + m, E - 1)];

    for (int v = v_lo; v < v_hi; ++v) {
        int end = row_start[v + 1];
        // residual loads overlap the gather latency below
        float res0 = xin[(size_t)v * ND + col0];
        float res1 = xin[(size_t)v * ND + col1];
        float part[8];
#pragma unroll
        for (int nt = 0; nt < 8; ++nt) part[nt] = 0.f;

        for (int base = beg; base < end; base += 16) {
            int2 pk = pk2;
            // next chunk: same node (base+16) or next node's first chunk (end)
            int nxt = (base + 16 < end) ? base + 16 : end;
            pk2 = pack[min(nxt + m, E - 1)];

            int rem = end - base;  // >= 1
            int s = (m < rem) ? pk.x : N;  // sentinel row kills pad lanes in relu

            // ---- batched loads: 8 dwordx4 x-fragments + 2 dwordx4 ea ----
            const unsigned short* xr = xpk + ((size_t)s * 16 + quad) * 16;
            short8 xh[4], xl[4];
#pragma unroll
            for (int kc = 0; kc < 4; ++kc) {
                xh[kc] = *(const short8*)(xr + kc * 64);
                xl[kc] = *(const short8*)(xr + kc * 64 + 8);
            }
            const float4* ar = (const float4*)(edge_attr + (size_t)pk.y * ED + quad * 8);
            float4 a0 = ar[0], a1 = ar[1];

            // ea A-fragment split hi/lo (exact)
            float af[8] = {a0.x, a0.y, a0.z, a0.w, a1.x, a1.y, a1.z, a1.w};
            short8 ah, al;
#pragma unroll
            for (int j = 0; j < 8; ++j) {
                unsigned short h = bf16_hi(af[j]);
                ah[j] = (short)h;
                al[j] = (short)bf16_hi(af[j] - bf16_f(h));
            }

#pragma unroll
            for (int nt = 0; nt < 8; ++nt) {
                f32x4 a = {0.f, 0.f, 0.f, 0.f};
                a = __builtin_amdgcn_mfma_f32_16x16x32_bf16(ah, bh[nt], a, 0, 0, 0);
                a = __builtin_amdgcn_mfma_f32_16x16x32_bf16(al, bh[nt], a, 0, 0, 0);
                a = __builtin_amdgcn_mfma_f32_16x16x32_bf16(xh[nt >> 1], idf[nt & 1], a,
                                                            0, 0, 0);
                a = __builtin_amdgcn_mfma_f32_16x16x32_bf16(xl[nt >> 1], idf[nt & 1], a,
                                                            0, 0, 0);
#pragma unroll
                for (int r = 0; r < 4; ++r)
                    part[nt] += fmaxf(a[r], 0.f);  // be already inside xpk
            }
        }
        // reduce over quads (cols live in lanes m, m+16, m+32, m+48)
#pragma unroll
        for (int nt = 0; nt < 8; ++nt) {
            float p = part[nt];
            p += __shfl_xor(p, 16, 64);
            p += __shfl_xor(p, 32, 64);
            part[nt] = p;
        }
        // quad q writes cols of tiles 2q, 2q+1
        float o0 = quad == 0 ? part[0] : quad == 1 ? part[2] : quad == 2 ? part[4] : part[6];
        float o1 = quad == 0 ? part[1] : quad == 1 ? part[3] : quad == 2 ? part[5] : part[7];
        hout[(size_t)v * ND + col0] = res0 + o0;
        hout[(size_t)v * ND + col1] = res1 + o1;
        beg = end;
    }
}

// Fused pair of GEMMs: C = maybe_relu2( relu(A@W1+b1) @ W2 + b2 ).
// Wave = 16 rows; intermediate goes through a per-wave LDS tile (132-pad rows).
// If xpk != nullptr, also emits xpk fragments of (C + ben) via the (dead by
// then) LDS tile -- fuses the next layer's xprep pass into this kernel.
#define LP 132  // padded LDS row stride (floats); 132*4B keeps 16B alignment
__global__ __launch_bounds__(256, 4) void mlp2_mfma(
    const float* __restrict__ A,
    const unsigned short* __restrict__ w1h, const unsigned short* __restrict__ w1l,
    const float* __restrict__ b1,
    const unsigned short* __restrict__ w2h, const unsigned short* __restrict__ w2l,
    const float* __restrict__ b2,
    float* __restrict__ C, int N, int relu2,
    const float* __restrict__ ben, unsigned short* __restrict__ xpk) {
    __shared__ float tile[4][16 * LP];
    int lane = threadIdx.x & 63;
    int wave = threadIdx.x >> 6;
    int gw = blockIdx.x * 4 + wave;
    int m0 = gw * 16;
    if (m0 >= N) return;
    int m = lane & 15;
    int quad = lane >> 4;
    float* T = tile[wave];

    // ---- stage 1: load A rows, split hi/lo ----
    int row = m0 + m;
    bool rok = row < N;
    short8 ah[4], al[4];
#pragma unroll
    for (int ks = 0; ks < 4; ++ks) {
        float f[8];
        if (rok) {
            const float4* p = (const float4*)(A + (size_t)row * ND + ks * 32 + quad * 8);
            float4 a0 = p[0], a1 = p[1];
            f[0] = a0.x; f[1] = a0.y; f[2] = a0.z; f[3] = a0.w;
            f[4] = a1.x; f[5] = a1.y; f[6] = a1.z; f[7] = a1.w;
        } else {
#pragma unroll
            for (int j = 0; j < 8; ++j) f[j] = 0.f;
        }
#pragma unroll
        for (int j = 0; j < 8; ++j) {
            unsigned short hh = bf16_hi(f[j]);
            ah[ks][j] = (short)hh;
            al[ks][j] = (short)bf16_hi(f[j] - bf16_f(hh));
        }
    }

    // GEMM1 -> bias + relu -> LDS tile (C/D layout: col=lane&15, row=quad*4+r)
#pragma unroll
    for (int nt = 0; nt < 8; ++nt) {
        f32x4 acc = {0.f, 0.f, 0.f, 0.f};
#pragma unroll
        for (int ks = 0; ks < 4; ++ks) {
            size_t off = ((size_t)(nt * 4 + ks) * 64 + lane) * 8;
            short8 bh = *(const short8*)(w1h + off);
            short8 bl = *(const short8*)(w1l + off);
            acc = __builtin_amdgcn_mfma_f32_16x16x32_bf16(ah[ks], bh, acc, 0, 0, 0);
            acc = __builtin_amdgcn_mfma_f32_16x16x32_bf16(al[ks], bh, acc, 0, 0, 0);
            acc = __builtin_amdgcn_mfma_f32_16x16x32_bf16(ah[ks], bl, acc, 0, 0, 0);
        }
        float bv = b1[nt * 16 + m];
#pragma unroll
        for (int r = 0; r < 4; ++r) {
            float o = acc[r] + bv;
            o = o > 0.f ? o : 0.f;
            T[(quad * 4 + r) * LP + nt * 16 + m] = o;
        }
    }

    // ---- stage 2: rows from LDS as A-fragments (same wave -> lgkmcnt wait) ----
    short8 ch[4], cl[4];
#pragma unroll
    for (int ks = 0; ks < 4; ++ks) {
        const float4* p = (const float4*)(T + m * LP + ks * 32 + quad * 8);
        float4 a0 = p[0], a1 = p[1];
        float f[8] = {a0.x, a0.y, a0.z, a0.w, a1.x, a1.y, a1.z, a1.w};
#pragma unroll
        for (int j = 0; j < 8; ++j) {
            unsigned short hh = bf16_hi(f[j]);
            ch[ks][j] = (short)hh;
            cl[ks][j] = (short)bf16_hi(f[j] - bf16_f(hh));
        }
    }

#pragma unroll
    for (int nt = 0; nt < 8; ++nt) {
        f32x4 acc = {0.f, 0.f, 0.f, 0.f};
#pragma unroll
        for (int ks = 0; ks < 4; ++ks) {
            size_t off = ((size_t)(nt * 4 + ks) * 64 + lane) * 8;
            short8 bh = *(const short8*)(w2h + off);
            short8 bl = *(const short8*)(w2l + off);
            acc = __builtin_amdgcn_mfma_f32_16x16x32_bf16(ch[ks], bh, acc, 0, 0, 0);
            acc = __builtin_amdgcn_mfma_f32_16x16x32_bf16(cl[ks], bh, acc, 0, 0, 0);
            acc = __builtin_amdgcn_mfma_f32_16x16x32_bf16(ch[ks], bl, acc, 0, 0, 0);
        }
        float bv = b2[nt * 16 + m];
#pragma unroll
        for (int r = 0; r < 4; ++r) {
            int rr = m0 + quad * 4 + r;
            float o = acc[r] + bv;
            if (relu2) o = o > 0.f ? o : 0.f;
            if (rr < N) C[(size_t)rr * ND + nt * 16 + m] = o;
            if (xpk) T[(quad * 4 + r) * LP + nt * 16 + m] = o;  // stash for pack
        }
    }

    // ---- fused xprep: pack (C + ben) rows -> xpk granules ----
    if (xpk) {
#pragma unroll
        for (int i = 0; i < 4; ++i) {
            int task = lane + 64 * i;  // 256 tasks = 16 rows x 16 granules
            int rl = task >> 4;
            int g = task & 15;
            int rr = m0 + rl;
            if (rr < N) {
                const float4* p = (const float4*)(T + rl * LP + g * 8);
                float4 a0 = p[0], a1 = p[1];
                float f[8] = {a0.x, a0.y, a0.z, a0.w, a1.x, a1.y, a1.z, a1.w};
                short8 h, l;
#pragma unroll
                for (int j = 0; j < 8; ++j) {
                    float fv = f[j] + ben[g * 8 + j];
                    unsigned short hh = bf16_hi(fv);
                    h[j] = (short)hh;
                    l[j] = (short)bf16_hi(fv - bf16_f(hh));
                }
                unsigned short* dst = xpk + ((size_t)rr * 16 + g) * 16;
                *(short8*)dst = h;
                *(short8*)(dst + 8) = l;
            }
        }
    }
}

extern "C" void kernel_launch(void* const* d_in, const int* in_sizes, int n_in,
                              void* d_out, int out_size, void* d_ws, size_t ws_size,
                              hipStream_t stream) {
    const float* x = (const float*)d_in[0];
    const int* ei = (const int*)d_in[1];  // int64 in reference -> int32 from harness
    const float* ea = (const float*)d_in[2];
    const float* w1_0 = (const float*)d_in[3];
    const float* b1_0 = (const float*)d_in[4];
    const float* w2_0 = (const float*)d_in[5];
    const float* b2_0 = (const float*)d_in[6];
    const float* we_0 = (const float*)d_in[7];
    const float* be_0 = (const float*)d_in[8];
    const float* w1_1 = (const float*)d_in[9];
    const float* b1_1 = (const float*)d_in[10];
    const float* w2_1 = (const float*)d_in[11];
    const float* b2_1 = (const float*)d_in[12];
    const float* we_1 = (const float*)d_in[13];
    const float* be_1 = (const float*)d_in[14];
    const float* fc1_w = (const float*)d_in[15];
    const float* fc1_b = (const float*)d_in[16];
    const float* fc2_w = (const float*)d_in[17];
    const float* fc2_b = (const float*)d_in[18];

    int N = in_sizes[0] / ND;
    int E = in_sizes[2] / ED;
    int NB = (N + 255) / 256;
    const int NW = 8192;  // agg waves (2048 blocks = 8 blocks/CU exact, no tail)

    float* bufA = (float*)d_ws;
    int* counts = (int*)(bufA + (size_t)N * ND);
    int* row_start = counts + N;        // N+1
    int* woff = row_start + (N + 1);    // N
    int* bsum = woff + N;               // NB
    int* bofs = bsum + NB;              // NB
    int* wstart = bofs + NB;            // NW+1
    int2* pack = (int2*)((((uintptr_t)(wstart + NW + 1)) + 15) & ~(uintptr_t)15);
    unsigned short* wfh = (unsigned short*)(pack + E);
    unsigned short* wfl = wfh + 6 * 16384;
    unsigned short* weh = wfl + 6 * 16384;  // 2 * 4096
    unsigned short* xpk = weh + 2 * 4096;   // (N+1) * 256 ushorts = 512B/row
    float* out = (float*)d_out;

    int ZB = (N + 255) / 256;
    int gx = ((N + 1) * 16 + 255) / 256;   // xprep role blocks
    int SB = (E + 255) / 256;              // scatter role blocks
    int WB = (NW + 1 + 255) / 256;         // wrange role blocks
    int gg = ((N + 15) / 16 + 3) / 4;      // fused-MLP blocks (4 waves x 16 rows)

    // ---- prep: 6 launches ----
    prepwx_kernel<<<ZB + 48 + 4 + gx, 256, 0, stream>>>(
        counts, N, w1_0, w2_0, w1_1, w2_1, fc1_w, fc2_w, wfh, wfl,
        we_0, we_1, weh, x, be_0, xpk);
    hist_kernel<<<(E + 255) / 256, 256, 0, stream>>>(ei, counts, E);
    bsum_kernel<<<NB, 256, 0, stream>>>(counts, bsum, N);
    scan_bsums<<<1, 256, 0, stream>>>(bsum, bofs, row_start + N, NB);
    expand_kernel<<<NB, 256, 0, stream>>>(counts, bofs, row_start, woff, N);
    scatter_wrange<<<SB + WB, 256, 0, stream>>>(ei, woff, pack, E, row_start, wstart,
                                                N, NW);

    // ---- layer 0 ----  agg0: x -> out; mlp0: out -> bufA (+ xpk for layer 1)
    agg_mfma<<<NW / 4, 256, 0, stream>>>(x, ea, xpk, weh, row_start, wstart, pack, out,
                                         N, E);
    mlp2_mfma<<<gg, 256, 0, stream>>>(out, wfh + 0 * 16384, wfl + 0 * 16384, b1_0,
                                      wfh + 1 * 16384, wfl + 1 * 16384, b2_0, bufA, N, 1,
                                      be_1, xpk);

    // ---- layer 1 ----  agg1: bufA -> out; mlp1: out -> bufA
    agg_mfma<<<NW / 4, 256, 0, stream>>>(bufA, ea, xpk, weh + 4096, row_start, wstart,
                                         pack, out, N, E);
    mlp2_mfma<<<gg, 256, 0, stream>>>(out, wfh + 2 * 16384, wfl + 2 * 16384, b1_1,
                                      wfh + 3 * 16384, wfl + 3 * 16384, b2_1, bufA, N, 1,
                                      nullptr, nullptr);

    // ---- head ----  bufA -> out (final)
    mlp2_mfma<<<gg, 256, 0, stream>>>(bufA, wfh + 4 * 16384, wfl + 4 * 16384, fc1_b,
                                      wfh + 5 * 16384, wfl + 5 * 16384, fc2_b, out, N, 0,
                                      nullptr, nullptr);
}